// Round 5
// baseline (147.085 us; speedup 1.0000x reference)
//
#include <hip/hip_runtime.h>

#define B_ 512
#define L_ 64
#define H_ 256
#define OUT_ 2048

typedef short bf16x8 __attribute__((ext_vector_type(8)));
typedef float f32x4 __attribute__((ext_vector_type(4)));

static __device__ __forceinline__ unsigned short f2bf(float f) {
  union { float f; unsigned int u; } v; v.f = f;
  unsigned int r = (v.u + 0x7FFFu + ((v.u >> 16) & 1u)) >> 16;
  return (unsigned short)r;
}
static __device__ __forceinline__ float bf2f(unsigned short s) {
  union { unsigned int u; float f; } v; v.u = ((unsigned int)s) << 16;
  return v.f;
}

// ---------------------------------------------------------------------------
// Pack Wc (256x2048 f32) and Wp (256x256 f32) into MFMA-B-fragment-major bf16:
// frag (col16, kt): 64 lanes x 16B; lane l holds
//   B[k = kt*32 + (l>>4)*8 + i][n = col16*16 + (l&15)], i = 0..7.
// ---------------------------------------------------------------------------
__global__ __launch_bounds__(256) void pack_kernel(
    const float* __restrict__ Wc, const float* __restrict__ Wp,
    unsigned short* __restrict__ WcB, unsigned short* __restrict__ WpB) {
  int bid = blockIdx.x;
  const float* W;
  unsigned short* dst;
  int ncols, col16;
  if (bid < 128) { W = Wc; dst = WcB; ncols = OUT_; col16 = bid; }
  else           { W = Wp; dst = WpB; ncols = H_;   col16 = bid - 128; }
  int tid = threadIdx.x, l = tid & 63, q = tid >> 6;
  int n = col16 * 16 + (l & 15), g = l >> 4;
#pragma unroll
  for (int kk = 0; kk < 2; ++kk) {
    int kt = q + kk * 4;
    bf16x8 v;
#pragma unroll
    for (int i = 0; i < 8; ++i)
      v[i] = (short)f2bf(W[(size_t)(kt * 32 + g * 8 + i) * ncols + n]);
    *(bf16x8*)&dst[(size_t)(col16 * 8 + kt) * 512 + l * 8] = v;
  }
}

// ---------------------------------------------------------------------------
// Rec kernel (verified R4 structure): sibling means + level-parallel
// recurrence in LDS, then dump z in A-fragment-packed layout:
//   zA frag f = mblk16*8 + kt (mblk16 = global row/16): lane l holds
//   z[row = mblk16*16 + (l&15)][k = kt*32 + (l>>4)*8 + i].
// ---------------------------------------------------------------------------
__global__ __launch_bounds__(256, 2) void rec_kernel(
    const float* __restrict__ mol, const int* __restrict__ pidx_g,
    const float* __restrict__ bp, const unsigned short* __restrict__ WpB,
    unsigned short* __restrict__ zA) {
  __shared__ unsigned short zbuf[65 * H_];
  __shared__ float scratch[63 * 128];
  __shared__ int pidx[L_];
  __shared__ float cnt[64];
  __shared__ int lvlcnt[64];
  __shared__ int lvlbase[64];
  __shared__ int chkbase[64];
  __shared__ int order_s[64];
  __shared__ int cstart_s[64];
  __shared__ int ccnt_s[64];
  __shared__ int nchunks_s;

  int b = blockIdx.x;
  int tid = threadIdx.x;
  int wv = tid >> 6, l = tid & 63, g = l >> 4, c = l & 15;

  if (tid < 64) pidx[tid] = pidx_g[b * L_ + tid];
  if (tid >= 64 && tid < 128) cnt[tid - 64] = 0.f;
  zbuf[tid] = 0;  // z row 0 = 0 (row 0 swizzle is identity)
  __syncthreads();
  if (tid >= 1 && tid < 64) atomicAdd(&cnt[pidx[tid]], 1.f);

  // ---- wave 0: schedule build (LDS-atomic ranks; within-level order free) --
  if (tid < 64) {
    int t = tid;
    lvlcnt[t] = 0;
    int pp = pidx[t];
    int lev = (t == 0) ? 0 : 1;
#pragma unroll
    for (int it = 0; it < 6; ++it) {
      int dp = __shfl(lev, pp);
      int pp2 = __shfl(pp, pp);
      lev += dp;
      pp = pp2;
    }
    int rank = 0;
    if (t >= 1) rank = atomicAdd(&lvlcnt[lev], 1);
    int lc = lvlcnt[t];
    int nchk = (lc + 15) >> 4;
    int offx = lc, chkx = nchk;
#pragma unroll
    for (int d = 1; d < 64; d <<= 1) {
      int u = __shfl_up(offx, d);
      int v2 = __shfl_up(chkx, d);
      if (t >= d) { offx += u; chkx += v2; }
    }
    lvlbase[t] = offx - lc;
    chkbase[t] = chkx - nchk;
    if (t == 63) nchunks_s = chkx;
    if (t >= 1) {
      int pos = lvlbase[lev] + rank;
      order_s[pos] = t;
      if ((rank & 15) == 0) {
        int cid = chkbase[lev] + (rank >> 4);
        cstart_s[cid] = pos;
        ccnt_s[cid] = min(16, lvlcnt[lev] - rank);
      }
    }
  }

  // ---- sibling means -> zbuf (bf16, swizzled), 2 H-halves ----
  const float* molb = mol + (size_t)b * L_ * H_;
  int hloc = tid & 127, tg2 = tid >> 7;
  for (int hb = 0; hb < 2; ++hb) {
    float mv[32];
#pragma unroll
    for (int k = 0; k < 32; ++k) {
      int t = 1 + tg2 + 2 * k;
      mv[k] = (t < 64) ? molb[t * H_ + hb * 128 + hloc] : 0.f;
    }
    for (int i = tid; i < 63 * 128; i += 256) scratch[i] = 0.f;
    __syncthreads();
#pragma unroll
    for (int k = 0; k < 32; ++k) {
      int t = 1 + tg2 + 2 * k;
      if (t < 64) atomicAdd(&scratch[pidx[t] * 128 + hloc], mv[k]);
    }
    __syncthreads();
#pragma unroll
    for (int k = 0; k < 32; ++k) {
      int t = 1 + tg2 + 2 * k;
      if (t < 64) {
        int p = pidx[t];
        float ccn = cnt[p] - 1.f;
        float v = (ccn > 0.f) ? (scratch[p * 128 + hloc] - mv[k]) / ccn : 0.f;
        zbuf[(t * H_ + hb * 128 + hloc) ^ ((t & 7) << 3)] = f2bf(v);
      }
    }
    __syncthreads();
  }

  // ---- Wp B-fragments (per-wave 64-col slice), step-invariant registers ----
  bf16x8 wfr[4][8];
#pragma unroll
  for (int nt = 0; nt < 4; ++nt)
#pragma unroll
    for (int kt = 0; kt < 8; ++kt)
      wfr[nt][kt] = *(const bf16x8*)&WpB[(size_t)((wv * 4 + nt) * 8 + kt) * 512 + l * 8];
  float bpv[4];
#pragma unroll
  for (int nt = 0; nt < 4; ++nt) bpv[nt] = bp[wv * 64 + nt * 16 + c];
  __syncthreads();

  // ---- level-parallel recurrence: one M=16 MFMA round per chunk ----
  int nch = nchunks_s;
  for (int ch = 0; ch < nch; ++ch) {
    int cs = cstart_s[ch], cc = ccnt_s[ch];
    int node = (c < cc) ? order_s[cs + c] : 64;
    int par = (node < 64) ? pidx[node] : 0;
    int sp = (par & 7) << 3;
    f32x4 a0 = {0.f, 0.f, 0.f, 0.f};
    f32x4 a1 = {0.f, 0.f, 0.f, 0.f};
    f32x4 a2 = {0.f, 0.f, 0.f, 0.f};
    f32x4 a3 = {0.f, 0.f, 0.f, 0.f};
#pragma unroll
    for (int kt = 0; kt < 8; ++kt) {
      bf16x8 av = *(const bf16x8*)&zbuf[par * H_ + ((kt * 32 + g * 8) ^ sp)];
      a0 = __builtin_amdgcn_mfma_f32_16x16x32_bf16(av, wfr[0][kt], a0, 0, 0, 0);
      a1 = __builtin_amdgcn_mfma_f32_16x16x32_bf16(av, wfr[1][kt], a1, 0, 0, 0);
      a2 = __builtin_amdgcn_mfma_f32_16x16x32_bf16(av, wfr[2][kt], a2, 0, 0, 0);
      a3 = __builtin_amdgcn_mfma_f32_16x16x32_bf16(av, wfr[3][kt], a3, 0, 0, 0);
    }
#pragma unroll
    for (int j = 0; j < 4; ++j) {
      int m = g * 4 + j;
      int nd = (m < cc) ? order_s[cs + m] : 64;
      int swn = (nd & 7) << 3;
      int base = nd * H_ + wv * 64 + c;
      int i0 = (base + 0) ^ swn, i1 = (base + 16) ^ swn;
      int i2 = (base + 32) ^ swn, i3 = (base + 48) ^ swn;
      float v0 = fmaxf(a0[j] + bpv[0], 0.f) + bf2f(zbuf[i0]);
      float v1 = fmaxf(a1[j] + bpv[1], 0.f) + bf2f(zbuf[i1]);
      float v2 = fmaxf(a2[j] + bpv[2], 0.f) + bf2f(zbuf[i2]);
      float v3 = fmaxf(a3[j] + bpv[3], 0.f) + bf2f(zbuf[i3]);
      zbuf[i0] = f2bf(v0);
      zbuf[i1] = f2bf(v1);
      zbuf[i2] = f2bf(v2);
      zbuf[i3] = f2bf(v3);
    }
    __syncthreads();
  }

  // ---- dump z as packed A-fragments (coalesced 1 KB stores) ----
  // wave wv owns local rows [wv*16, wv*16+16)
  int row = wv * 16 + c;
#pragma unroll
  for (int kt = 0; kt < 8; ++kt) {
    bf16x8 v = *(const bf16x8*)&zbuf[row * H_ + ((kt * 32 + g * 8) ^ ((row & 7) << 3))];
    *(bf16x8*)&zA[(size_t)((b * 4 + wv) * 8 + kt) * 512 + l * 8] = v;
  }
}

// ---------------------------------------------------------------------------
// GEMM kernel: out = zA(32768x256 packed bf16) @ WcB(256x2048 packed) + bc.
// WG = 64 rows x 256 cols, wave = 64 cols. All A/B fragment loads are single
// coalesced dwordx4 from L2 (XCD-decode keeps each XCD's working set = its
// 2 MB zA slice + 1 MB WcB). Epilogue: LDS-staged, 512B-contiguous
// nontemporal f32x4 stores.
// ---------------------------------------------------------------------------
__global__ __launch_bounds__(256, 3) void gemm_kernel(
    const unsigned short* __restrict__ zA, const unsigned short* __restrict__ WcB,
    const float* __restrict__ bc, float* __restrict__ out) {
  __shared__ float st[64 * 128];  // 32 KB staging
  int Lb = blockIdx.x;
  // XCD-aware decode: xcd = Lb&7 (dispatch round-robin); all 8 n-splits of a
  // given mb land on the same xcd -> A panel L2-resident.
  int xcd = Lb & 7, idx = Lb >> 3;
  int mb = (xcd << 6) | (idx & 63);  // 0..511 (64-row panel)
  int nb = idx >> 6;                 // 0..7   (256-col span)
  int tid = threadIdx.x;
  int wv = tid >> 6, l = tid & 63, g = l >> 4, c = l & 15;

  float bcv[4];
#pragma unroll
  for (int nt = 0; nt < 4; ++nt) bcv[nt] = bc[nb * 256 + wv * 64 + nt * 16 + c];

  f32x4 acc[4][4] = {};
#pragma unroll
  for (int kt = 0; kt < 8; ++kt) {
    bf16x8 a[4], bfr[4];
#pragma unroll
    for (int mt = 0; mt < 4; ++mt)
      a[mt] = *(const bf16x8*)&zA[(size_t)((mb * 4 + mt) * 8 + kt) * 512 + l * 8];
#pragma unroll
    for (int nt = 0; nt < 4; ++nt) {
      int col16 = nb * 16 + wv * 4 + nt;
      bfr[nt] = *(const bf16x8*)&WcB[(size_t)(col16 * 8 + kt) * 512 + l * 8];
    }
#pragma unroll
    for (int nt = 0; nt < 4; ++nt)
#pragma unroll
      for (int mt = 0; mt < 4; ++mt)
        acc[mt][nt] = __builtin_amdgcn_mfma_f32_16x16x32_bf16(
            a[mt], bfr[nt], acc[mt][nt], 0, 0, 0);
  }

  // ---- staged epilogue: 2 rounds of 64x128 through LDS ----
#pragma unroll 1
  for (int r = 0; r < 2; ++r) {
    __syncthreads();
    if ((wv >> 1) == r) {
      int half = (wv & 1) * 64;
#pragma unroll
      for (int mt = 0; mt < 4; ++mt)
#pragma unroll
        for (int nt = 0; nt < 4; ++nt)
#pragma unroll
          for (int j = 0; j < 4; ++j)
            st[(mt * 16 + g * 4 + j) * 128 + half + nt * 16 + c] =
                acc[mt][nt][j] + bcv[nt];
    }
    __syncthreads();
#pragma unroll
    for (int s = 0; s < 8; ++s) {
      int flat = tid + s * 256;        // 0..2047 float4 units
      int row = flat >> 5, c4 = flat & 31;
      f32x4 v = *(f32x4*)&st[row * 128 + c4 * 4];
      __builtin_nontemporal_store(
          v, (f32x4*)&out[(size_t)(mb * 64 + row) * OUT_ + nb * 256 + r * 128 + c4 * 4]);
    }
  }
}

extern "C" void kernel_launch(void* const* d_in, const int* in_sizes, int n_in,
                              void* d_out, int out_size, void* d_ws, size_t ws_size,
                              hipStream_t stream) {
  const float* mol = (const float*)d_in[0];
  const int* pidx = (const int*)d_in[1];
  const float* Wp = (const float*)d_in[2];
  const float* bp = (const float*)d_in[3];
  const float* Wc = (const float*)d_in[4];
  const float* bc = (const float*)d_in[5];
  float* out = (float*)d_out;

  unsigned short* WcB = (unsigned short*)d_ws;                  // 1 MB
  unsigned short* WpB = WcB + (size_t)128 * 8 * 512;            // 128 KB
  unsigned short* zA  = WpB + (size_t)16 * 8 * 512;             // 16 MB

  pack_kernel<<<144, 256, 0, stream>>>(Wc, Wp, WcB, WpB);
  rec_kernel<<<B_, 256, 0, stream>>>(mol, pidx, bp, WpB, zA);
  gemm_kernel<<<4096, 256, 0, stream>>>(zA, WcB, bc, out);
}